// Round 9
// baseline (448.055 us; speedup 1.0000x reference)
//
#include <hip/hip_runtime.h>
#include <stdint.h>

typedef unsigned short u16;
typedef __attribute__((ext_vector_type(4))) float f32x4;
typedef __attribute__((ext_vector_type(8))) __bf16 bf16x8;

#define AS1(p) ((const __attribute__((address_space(1))) unsigned int*)(p))
#define AS3(p) ((__attribute__((address_space(3))) unsigned int*)(p))
#define GL2LDS16(g, l) __builtin_amdgcn_global_load_lds(AS1(g), AS3(l), 16, 0, 0)

__device__ __forceinline__ u16 f2bf(float x) {
  union { float f; uint32_t u; } v; v.f = x;
  return (u16)((v.u + 0x7fffu + ((v.u >> 16) & 1u)) >> 16);
}
__device__ __forceinline__ uint32_t pkbf(float a, float b) {
  union { __bf16 h[2]; uint32_t u; } x;
  x.h[0] = (__bf16)a; x.h[1] = (__bf16)b;
  return x.u;
}
__device__ __forceinline__ void store_c(u16* p, float v) { *p = f2bf(v); }
__device__ __forceinline__ void store_c(float* p, float v) { *p = v; }

// ---------------- fused fp32 -> bf16 convert (w_q | w_out | k) ----------------
__global__ __launch_bounds__(256) void cvt3_kernel(const float* __restrict__ a,
                                                   const float* __restrict__ bb,
                                                   const float* __restrict__ c,
                                                   u16* __restrict__ oa,
                                                   u16* __restrict__ ob,
                                                   u16* __restrict__ oc) {
  const int stride = gridDim.x * blockDim.x;
  for (int i = blockIdx.x * blockDim.x + threadIdx.x; i < 2621440; i += stride) {
    const float* src; u16* dst; int idx;
    if (i < 1048576)      { src = a;  dst = oa; idx = i; }
    else if (i < 2097152) { src = bb; dst = ob; idx = i - 1048576; }
    else                  { src = c;  dst = oc; idx = i - 2097152; }
    const float4 v = ((const float4*)src)[idx];
    ushort4 o;
    o.x = f2bf(v.x); o.y = f2bf(v.y); o.z = f2bf(v.z); o.w = f2bf(v.w);
    ((ushort4*)dst)[idx] = o;
  }
}

// ---------------- V transpose: (B,Tk,G,128) fp32 -> (B,G,128,Tk) bf16 ----------------
__global__ __launch_bounds__(256) void vtrans_kernel(const float* __restrict__ v,
                                                     u16* __restrict__ vt) {
  __shared__ u16 tile[64][65];
  const int tid = threadIdx.x;
  const int t0 = blockIdx.x * 64;
  const int bg = blockIdx.y;             // b*4+g
  const int b = bg >> 2, g = bg & 3;
  const int d0 = blockIdx.z * 64;
#pragma unroll
  for (int it = 0; it < 4; ++it) {
    const int i = (tid >> 4) + it * 16;
    const int j = (tid & 15) * 4;
    const float4 x = *(const float4*)(v + (((size_t)(b * 2048 + t0 + i) * 4 + g) * 128 + d0 + j));
    tile[i][j + 0] = f2bf(x.x);
    tile[i][j + 1] = f2bf(x.y);
    tile[i][j + 2] = f2bf(x.z);
    tile[i][j + 3] = f2bf(x.w);
  }
  __syncthreads();
  const int dd = tid >> 2;
#pragma unroll
  for (int it = 0; it < 4; ++it) {
    const int tt = (tid & 3) * 16 + it * 4;
    ushort4 o;
    o.x = tile[tt + 0][dd];
    o.y = tile[tt + 1][dd];
    o.z = tile[tt + 2][dd];
    o.w = tile[tt + 3][dd];
    *(ushort4*)(vt + (((size_t)bg * 128 + d0 + dd) * 2048 + t0 + tt)) = o;
  }
}

// ---------------- bf16 GEMM: C[m][n] = scale * sum_k A[m][k]*Bm[n][k] --------
template<typename OutT>
__global__ __launch_bounds__(256) void gemm_bt(const u16* __restrict__ A,
                                               const u16* __restrict__ Bm,
                                               OutT* __restrict__ C,
                                               int M, int N, int K, float scale) {
  __shared__ __align__(16) u16 As[128 * 32];
  __shared__ __align__(16) u16 Bs[128 * 32];
  const int tid = threadIdx.x;
  const int lane = tid & 63;
  const int w = tid >> 6, wm = w >> 1, wn = w & 1;
  const int m0 = blockIdx.y * 128, n0 = blockIdx.x * 128;
  f32x4 acc[4][4] = {};
  for (int kt = 0; kt < K; kt += 32) {
    __syncthreads();
#pragma unroll
    for (int j = 0; j < 2; ++j) {
      const int c = j * 256 + tid;
      const int row = c >> 2, ch = c & 3;
      GL2LDS16(A + (size_t)(m0 + row) * K + kt + ch * 8, As + (size_t)c * 8);
      GL2LDS16(Bm + (size_t)(n0 + row) * K + kt + ch * 8, Bs + (size_t)c * 8);
    }
    __syncthreads();
    bf16x8 af[4], bfr[4];
#pragma unroll
    for (int i = 0; i < 4; ++i) {
      af[i]  = *(const bf16x8*)(As + (wm * 64 + i * 16 + (lane & 15)) * 32 + (lane >> 4) * 8);
      bfr[i] = *(const bf16x8*)(Bs + (wn * 64 + i * 16 + (lane & 15)) * 32 + (lane >> 4) * 8);
    }
#pragma unroll
    for (int mi = 0; mi < 4; ++mi)
#pragma unroll
      for (int ni = 0; ni < 4; ++ni)
        acc[mi][ni] = __builtin_amdgcn_mfma_f32_16x16x32_bf16(af[mi], bfr[ni], acc[mi][ni], 0, 0, 0);
  }
#pragma unroll
  for (int mi = 0; mi < 4; ++mi)
#pragma unroll
    for (int r = 0; r < 4; ++r) {
      const int row = m0 + wm * 64 + mi * 16 + (lane >> 4) * 4 + r;
#pragma unroll
      for (int ni = 0; ni < 4; ++ni) {
        const int col = n0 + wn * 64 + ni * 16 + (lane & 15);
        store_c(C + (size_t)row * N + col, acc[mi][ni][r] * scale);
      }
    }
}

// ---------------- RMSNorm (rows of 2048) -> bf16 ----------------
__global__ __launch_bounds__(256) void rmsnorm_kernel(const float* __restrict__ x,
                                                      const float* __restrict__ w,
                                                      u16* __restrict__ out) {
  const int row = blockIdx.x;            // 4096 rows
  const int tid = threadIdx.x;
  const float* xr = x + (size_t)row * 2048;
  const float4 a0 = ((const float4*)xr)[tid];
  const float4 a1 = ((const float4*)xr)[tid + 256];
  float ss = a0.x*a0.x + a0.y*a0.y + a0.z*a0.z + a0.w*a0.w
           + a1.x*a1.x + a1.y*a1.y + a1.z*a1.z + a1.w*a1.w;
#pragma unroll
  for (int m = 1; m < 64; m <<= 1) ss += __shfl_xor(ss, m);
  __shared__ float red[4];
  if ((tid & 63) == 0) red[tid >> 6] = ss;
  __syncthreads();
  const float tot = red[0] + red[1] + red[2] + red[3];
  const float sc = rsqrtf(tot * (1.0f / 2048.0f) + 1e-6f);
  const float4 w0 = ((const float4*)w)[tid];
  const float4 w1 = ((const float4*)w)[tid + 256];
  u16* orow = out + (size_t)row * 2048;
  ushort4 o0, o1;
  o0.x = f2bf(a0.x * sc * w0.x); o0.y = f2bf(a0.y * sc * w0.y);
  o0.z = f2bf(a0.z * sc * w0.z); o0.w = f2bf(a0.w * sc * w0.w);
  o1.x = f2bf(a1.x * sc * w1.x); o1.y = f2bf(a1.y * sc * w1.y);
  o1.z = f2bf(a1.z * sc * w1.z); o1.w = f2bf(a1.w * sc * w1.w);
  ((ushort4*)orow)[tid] = o0;
  ((ushort4*)orow)[tid + 256] = o1;
}

// ---------------- GQA flash attention (KVBLK=32, 4 blocks/CU) ----------------
// grid: (Tq/128, B*H). block 256 = 4 waves; wave w owns q-rows [w*32, w*32+32).
// q (pre-scaled by 1/sqrt(d)*log2e): (B,Tq,2048) bf16; k: (B,Tk,G,128) bf16;
// vt: (B,G,128,Tk) bf16.
__global__ __launch_bounds__(256, 4) void attn_kernel(const u16* __restrict__ q,
                                                      const u16* __restrict__ kbf,
                                                      const u16* __restrict__ vt,
                                                      u16* __restrict__ ctx) {
  // LDS 40960 B (4 blocks/CU): Ks[2] 2x8192B | VT[2] 2x8192B | Ps 4 waves x 2048B
  // Qs (32768B, prologue only) unions with Ks+VT region.
  __shared__ __align__(16) char smem[40960];
  u16* const Qs  = (u16*)smem;
  u16* const Ks  = (u16*)smem;               // + buf*4096 elements
  u16* const VTb = (u16*)(smem + 16384);     // + buf*4096 elements
  const int tid = threadIdx.x;
  const int lane = tid & 63;
  const int w = tid >> 6;
  const int l15 = lane & 15, lhi = lane >> 4;
  u16* const PsW = (u16*)(smem + 32768) + w * 1024;  // [32 q][32 key], e^=(row&6)<<2 swz
  const int qt = blockIdx.x;
  const int bh = blockIdx.y;
  const int b = bh >> 4, h = bh & 15, g = h >> 2;
  const size_t qbase  = ((size_t)(b * 2048 + qt * 128)) * 2048 + h * 128;
  const size_t kbase  = (size_t)b * 1048576 + g * 128;            // k elements
  const size_t vtbase = (size_t)(b * 4 + g) * 262144;             // vt elements

  // ---- prologue: stage Q (swizzled), read qf ----
#pragma unroll
  for (int j = 0; j < 8; ++j) {
    const int c = j * 256 + tid;
    const int row = c >> 4;
    const int dim0 = ((c & 15) ^ (row & 7)) << 3;
    GL2LDS16(q + qbase + (size_t)row * 2048 + dim0, Qs + (size_t)c * 8);
  }
  __syncthreads();
  bf16x8 qf[2][4];
#pragma unroll
  for (int qs = 0; qs < 2; ++qs) {
    const int qrow = w * 32 + qs * 16 + l15;
#pragma unroll
    for (int dk = 0; dk < 4; ++dk) {
      const int el = qrow * 128 + ((dk * 32 + lhi * 8) ^ ((qrow & 7) << 3));
      qf[qs][dk] = *(const bf16x8*)(Qs + el);
    }
  }
  __syncthreads();   // qf reads drained before Ks[0]/VT[0] overwrite

  // staging: K [32 keys][128 dims] row&7 swizzle; V^T [128 dims][32 keys] row&6 swizzle
  auto stageK = [&](int buf, int kt0) {
    u16* Kb = Ks + buf * 4096;
#pragma unroll
    for (int j = 0; j < 2; ++j) {
      const int c = j * 256 + tid;
      const int key = c >> 4;
      const int dim0 = ((c & 15) ^ (key & 7)) << 3;
      GL2LDS16(kbf + kbase + (size_t)(kt0 + key) * 512 + dim0, Kb + (size_t)c * 8);
    }
  };
  auto stageV = [&](int buf, int kt0) {
    u16* Vb = VTb + buf * 4096;
#pragma unroll
    for (int j = 0; j < 2; ++j) {
      const int c = j * 256 + tid;
      const int d = c >> 2;                                  // 0..127
      const int e0 = (((c & 3) << 3) ^ ((d & 6) << 2));      // pre-swizzled source col
      GL2LDS16(vt + vtbase + (size_t)d * 2048 + kt0 + e0, Vb + (size_t)c * 8);
    }
  };

  // ---- stage tile 0 ----
  stageK(0, 0);
  stageV(0, 0);
  __syncthreads();

  f32x4 cacc[8][2] = {};          // O^T: dim = nd*16+lhi*4+r, q = qs*16+l15
  float mrow[2], lrow[2];
#pragma unroll
  for (int qs = 0; qs < 2; ++qs) { mrow[qs] = -3.0e38f; lrow[qs] = 0.f; }

  int cur = 0;
  for (int kt0 = 0; kt0 < 2048; kt0 += 32) {
    const int nxt = cur ^ 1;
    const bool pref = (kt0 + 32) < 2048;
    if (pref) { stageK(nxt, kt0 + 32); stageV(nxt, kt0 + 32); }   // issue-early

    // QK^T swapped: st[ni][qs] = S^T[key = ni*16+lhi*4+r][q = qs*16+l15]
    const u16* Kb = Ks + cur * 4096;
    f32x4 st[2][2] = {};
#pragma unroll
    for (int dk = 0; dk < 4; ++dk) {
      bf16x8 kf[2];
#pragma unroll
      for (int ni = 0; ni < 2; ++ni) {
        const int key = ni * 16 + l15;
        const int el = key * 128 + ((dk * 32 + lhi * 8) ^ ((key & 7) << 3));
        kf[ni] = *(const bf16x8*)(Kb + el);
      }
      __builtin_amdgcn_s_setprio(1);
#pragma unroll
      for (int ni = 0; ni < 2; ++ni)
#pragma unroll
        for (int qs = 0; qs < 2; ++qs)
          st[ni][qs] = __builtin_amdgcn_mfma_f32_16x16x32_bf16(kf[ni], qf[qs][dk], st[ni][qs], 0, 0, 0);
      __builtin_amdgcn_s_setprio(0);
    }

    // online softmax per q-column (scores already in exp2 domain)
#pragma unroll
    for (int qs = 0; qs < 2; ++qs) {
      float pm = -3.0e38f;
#pragma unroll
      for (int ni = 0; ni < 2; ++ni)
#pragma unroll
        for (int r = 0; r < 4; ++r) pm = fmaxf(pm, st[ni][qs][r]);
      pm = fmaxf(pm, __shfl_xor(pm, 16));
      pm = fmaxf(pm, __shfl_xor(pm, 32));
      if (!__all(pm <= mrow[qs] + 8.0f)) {       // defer-max (T13)
        const float mnew = fmaxf(mrow[qs], pm);
        const float f = exp2f(mrow[qs] - mnew);
        mrow[qs] = mnew;
        lrow[qs] *= f;
#pragma unroll
        for (int nd = 0; nd < 8; ++nd) cacc[nd][qs] *= f;
      }
      float ps = 0.f;
      const int row = qs * 16 + l15;
      const int rsw = (row & 6) << 2;
#pragma unroll
      for (int ni = 0; ni < 2; ++ni) {
        const float a0 = exp2f(st[ni][qs][0] - mrow[qs]);
        const float a1 = exp2f(st[ni][qs][1] - mrow[qs]);
        const float a2 = exp2f(st[ni][qs][2] - mrow[qs]);
        const float a3 = exp2f(st[ni][qs][3] - mrow[qs]);
        ps += (a0 + a1) + (a2 + a3);
        uint2 val; val.x = pkbf(a0, a1); val.y = pkbf(a2, a3);
        *(uint2*)(PsW + row * 32 + ((ni * 16 + lhi * 4) ^ rsw)) = val;
      }
      ps += __shfl_xor(ps, 16);
      ps += __shfl_xor(ps, 32);
      lrow[qs] += ps;
    }

    // PV: O^T[dim][q] += V^T * P (single K=32 chunk)
    const u16* Vb = VTb + cur * 4096;
    bf16x8 pf[2];
#pragma unroll
    for (int qs = 0; qs < 2; ++qs) {
      const int row = qs * 16 + l15;
      pf[qs] = *(const bf16x8*)(PsW + row * 32 + ((lhi * 8) ^ ((row & 6) << 2)));
    }
    __builtin_amdgcn_s_setprio(1);
#pragma unroll
    for (int nd = 0; nd < 8; ++nd) {
      const int rowv = nd * 16 + l15;
      const bf16x8 vf = *(const bf16x8*)(Vb + rowv * 32 + ((lhi * 8) ^ ((rowv & 6) << 2)));
#pragma unroll
      for (int qs = 0; qs < 2; ++qs)
        cacc[nd][qs] = __builtin_amdgcn_mfma_f32_16x16x32_bf16(vf, pf[qs], cacc[nd][qs], 0, 0, 0);
    }
    __builtin_amdgcn_s_setprio(0);

    __syncthreads();   // drains gl2lds for nxt + protects buffers
    cur = nxt;
  }

  // epilogue: O^T -> ctx, normalize by row sum
  const int qrow_base = b * 2048 + qt * 128 + w * 32;
#pragma unroll
  for (int qs = 0; qs < 2; ++qs) {
    const float inv = 1.0f / lrow[qs];
    const int row = qrow_base + qs * 16 + l15;
    u16* orow = ctx + (size_t)row * 2048 + h * 128 + lhi * 4;
#pragma unroll
    for (int nd = 0; nd < 8; ++nd) {
      uint2 val;
      val.x = pkbf(cacc[nd][qs][0] * inv, cacc[nd][qs][1] * inv);
      val.y = pkbf(cacc[nd][qs][2] * inv, cacc[nd][qs][3] * inv);
      *(uint2*)(orow + nd * 16) = val;
    }
  }
}

extern "C" void kernel_launch(void* const* d_in, const int* in_sizes, int n_in,
                              void* d_out, int out_size, void* d_ws, size_t ws_size,
                              hipStream_t stream) {
  const float* x_q    = (const float*)d_in[0];
  const float* k_ctx  = (const float*)d_in[1];
  const float* v_ctx  = (const float*)d_in[2];
  const float* w_q    = (const float*)d_in[3];
  const float* w_out  = (const float*)d_in[4];
  const float* norm_w = (const float*)d_in[5];
  float* out = (float*)d_out;

  char* ws = (char*)d_ws;
  u16* wq_bf = (u16*)(ws);
  u16* wo_bf = (u16*)(ws + 8388608);
  u16* k_bf  = (u16*)(ws + 16777216);
  u16* v_t   = (u16*)(ws + 20971520);   // (B,G,128,Tk) bf16, 4 MB
  u16* xn    = (u16*)(ws + 25165824);
  u16* qb    = (u16*)(ws + 41943040);
  u16* ctxb  = xn;  // xn dead after q-proj

  const float kscale = 0.08838834764831845f * 1.4426950408889634f; // 1/sqrt(128)*log2(e)

  cvt3_kernel<<<2048, 256, 0, stream>>>(w_q, w_out, k_ctx, wq_bf, wo_bf, k_bf);
  vtrans_kernel<<<dim3(32, 8, 2), 256, 0, stream>>>(v_ctx, v_t);
  rmsnorm_kernel<<<4096, 256, 0, stream>>>(x_q, norm_w, xn);
  gemm_bt<u16><<<dim3(16, 32), 256, 0, stream>>>(xn, wq_bf, qb, 4096, 2048, 2048, kscale);
  attn_kernel<<<dim3(16, 32), 256, 0, stream>>>(qb, k_bf, v_t, ctxb);
  gemm_bt<float><<<dim3(16, 32), 256, 0, stream>>>(ctxb, wo_bf, out, 4096, 2048, 2048, 1.0f);
}

// Round 10
// 329.722 us; speedup vs baseline: 1.3589x; 1.3589x over previous
//
#include <hip/hip_runtime.h>
#include <stdint.h>

typedef unsigned short u16;
typedef __attribute__((ext_vector_type(4))) float f32x4;
typedef __attribute__((ext_vector_type(8))) __bf16 bf16x8;

#define AS1(p) ((const __attribute__((address_space(1))) unsigned int*)(p))
#define AS3(p) ((__attribute__((address_space(3))) unsigned int*)(p))
#define GL2LDS16(g, l) __builtin_amdgcn_global_load_lds(AS1(g), AS3(l), 16, 0, 0)

__device__ __forceinline__ u16 f2bf(float x) {
  union { float f; uint32_t u; } v; v.f = x;
  return (u16)((v.u + 0x7fffu + ((v.u >> 16) & 1u)) >> 16);
}
__device__ __forceinline__ uint32_t pkbf(float a, float b) {
  union { __bf16 h[2]; uint32_t u; } x;
  x.h[0] = (__bf16)a; x.h[1] = (__bf16)b;
  return x.u;
}
__device__ __forceinline__ void store_c(u16* p, float v) { *p = f2bf(v); }
__device__ __forceinline__ void store_c(float* p, float v) { *p = v; }

// ---------------- fused fp32 -> bf16 convert (w_q | w_out | k) ----------------
__global__ __launch_bounds__(256) void cvt3_kernel(const float* __restrict__ a,
                                                   const float* __restrict__ bb,
                                                   const float* __restrict__ c,
                                                   u16* __restrict__ oa,
                                                   u16* __restrict__ ob,
                                                   u16* __restrict__ oc) {
  const int stride = gridDim.x * blockDim.x;
  for (int i = blockIdx.x * blockDim.x + threadIdx.x; i < 2621440; i += stride) {
    const float* src; u16* dst; int idx;
    if (i < 1048576)      { src = a;  dst = oa; idx = i; }
    else if (i < 2097152) { src = bb; dst = ob; idx = i - 1048576; }
    else                  { src = c;  dst = oc; idx = i - 2097152; }
    const float4 v = ((const float4*)src)[idx];
    ushort4 o;
    o.x = f2bf(v.x); o.y = f2bf(v.y); o.z = f2bf(v.z); o.w = f2bf(v.w);
    ((ushort4*)dst)[idx] = o;
  }
}

// ---------------- V transpose: (B,Tk,G,128) fp32 -> (B,G,128,Tk) bf16 ----------------
__global__ __launch_bounds__(256) void vtrans_kernel(const float* __restrict__ v,
                                                     u16* __restrict__ vt) {
  __shared__ u16 tile[64][65];
  const int tid = threadIdx.x;
  const int t0 = blockIdx.x * 64;
  const int bg = blockIdx.y;             // b*4+g
  const int b = bg >> 2, g = bg & 3;
  const int d0 = blockIdx.z * 64;
#pragma unroll
  for (int it = 0; it < 4; ++it) {
    const int i = (tid >> 4) + it * 16;
    const int j = (tid & 15) * 4;
    const float4 x = *(const float4*)(v + (((size_t)(b * 2048 + t0 + i) * 4 + g) * 128 + d0 + j));
    tile[i][j + 0] = f2bf(x.x);
    tile[i][j + 1] = f2bf(x.y);
    tile[i][j + 2] = f2bf(x.z);
    tile[i][j + 3] = f2bf(x.w);
  }
  __syncthreads();
  const int dd = tid >> 2;
#pragma unroll
  for (int it = 0; it < 4; ++it) {
    const int tt = (tid & 3) * 16 + it * 4;
    ushort4 o;
    o.x = tile[tt + 0][dd];
    o.y = tile[tt + 1][dd];
    o.z = tile[tt + 2][dd];
    o.w = tile[tt + 3][dd];
    *(ushort4*)(vt + (((size_t)bg * 128 + d0 + dd) * 2048 + t0 + tt)) = o;
  }
}

// ------- bf16 GEMM, 2-phase double-buffered: C = scale * A @ Bm^T -------
template<typename OutT>
__global__ __launch_bounds__(256) void gemm_bt(const u16* __restrict__ A,
                                               const u16* __restrict__ Bm,
                                               OutT* __restrict__ C,
                                               int M, int N, int K, float scale) {
  __shared__ __align__(16) u16 As[2][128 * 32];
  __shared__ __align__(16) u16 Bs[2][128 * 32];
  const int tid = threadIdx.x;
  const int lane = tid & 63;
  const int w = tid >> 6, wm = w >> 1, wn = w & 1;
  const int m0 = blockIdx.y * 128, n0 = blockIdx.x * 128;

  auto stage = [&](int buf, int kt) {
#pragma unroll
    for (int j = 0; j < 2; ++j) {
      const int c = j * 256 + tid;
      const int row = c >> 2, ch = c & 3;
      GL2LDS16(A + (size_t)(m0 + row) * K + kt + ch * 8, As[buf] + (size_t)c * 8);
      GL2LDS16(Bm + (size_t)(n0 + row) * K + kt + ch * 8, Bs[buf] + (size_t)c * 8);
    }
  };

  f32x4 acc[4][4] = {};
  stage(0, 0);
  __syncthreads();
  int cur = 0;
  for (int kt = 0; kt < K; kt += 32) {
    if (kt + 32 < K) stage(cur ^ 1, kt + 32);   // issue-early; lands after this tile's MFMA
    bf16x8 af[4], bfr[4];
#pragma unroll
    for (int i = 0; i < 4; ++i) {
      af[i]  = *(const bf16x8*)(As[cur] + (wm * 64 + i * 16 + (lane & 15)) * 32 + (lane >> 4) * 8);
      bfr[i] = *(const bf16x8*)(Bs[cur] + (wn * 64 + i * 16 + (lane & 15)) * 32 + (lane >> 4) * 8);
    }
    __builtin_amdgcn_s_setprio(1);
#pragma unroll
    for (int mi = 0; mi < 4; ++mi)
#pragma unroll
      for (int ni = 0; ni < 4; ++ni)
        acc[mi][ni] = __builtin_amdgcn_mfma_f32_16x16x32_bf16(af[mi], bfr[ni], acc[mi][ni], 0, 0, 0);
    __builtin_amdgcn_s_setprio(0);
    __syncthreads();   // one barrier per K-step: drains prefetch vmcnt + protects cur
    cur ^= 1;
  }
#pragma unroll
  for (int mi = 0; mi < 4; ++mi)
#pragma unroll
    for (int r = 0; r < 4; ++r) {
      const int row = m0 + wm * 64 + mi * 16 + (lane >> 4) * 4 + r;
#pragma unroll
      for (int ni = 0; ni < 4; ++ni) {
        const int col = n0 + wn * 64 + ni * 16 + (lane & 15);
        store_c(C + (size_t)row * N + col, acc[mi][ni][r] * scale);
      }
    }
}

// ---------------- RMSNorm (rows of 2048) -> bf16 ----------------
__global__ __launch_bounds__(256) void rmsnorm_kernel(const float* __restrict__ x,
                                                      const float* __restrict__ w,
                                                      u16* __restrict__ out) {
  const int row = blockIdx.x;            // 4096 rows
  const int tid = threadIdx.x;
  const float* xr = x + (size_t)row * 2048;
  const float4 a0 = ((const float4*)xr)[tid];
  const float4 a1 = ((const float4*)xr)[tid + 256];
  float ss = a0.x*a0.x + a0.y*a0.y + a0.z*a0.z + a0.w*a0.w
           + a1.x*a1.x + a1.y*a1.y + a1.z*a1.z + a1.w*a1.w;
#pragma unroll
  for (int m = 1; m < 64; m <<= 1) ss += __shfl_xor(ss, m);
  __shared__ float red[4];
  if ((tid & 63) == 0) red[tid >> 6] = ss;
  __syncthreads();
  const float tot = red[0] + red[1] + red[2] + red[3];
  const float sc = rsqrtf(tot * (1.0f / 2048.0f) + 1e-6f);
  const float4 w0 = ((const float4*)w)[tid];
  const float4 w1 = ((const float4*)w)[tid + 256];
  u16* orow = out + (size_t)row * 2048;
  ushort4 o0, o1;
  o0.x = f2bf(a0.x * sc * w0.x); o0.y = f2bf(a0.y * sc * w0.y);
  o0.z = f2bf(a0.z * sc * w0.z); o0.w = f2bf(a0.w * sc * w0.w);
  o1.x = f2bf(a1.x * sc * w1.x); o1.y = f2bf(a1.y * sc * w1.y);
  o1.z = f2bf(a1.z * sc * w1.z); o1.w = f2bf(a1.w * sc * w1.w);
  ((ushort4*)orow)[tid] = o0;
  ((ushort4*)orow)[tid + 256] = o1;
}

// ---------------- GQA flash attention (KVBLK=32, no forced min-occupancy) -------------
// grid: (Tq/128, B*H). block 256 = 4 waves; wave w owns q-rows [w*32, w*32+32).
// q (pre-scaled by 1/sqrt(d)*log2e): (B,Tq,2048) bf16; k: (B,Tk,G,128) bf16;
// vt: (B,G,128,Tk) bf16.
__global__ __launch_bounds__(256) void attn_kernel(const u16* __restrict__ q,
                                                   const u16* __restrict__ kbf,
                                                   const u16* __restrict__ vt,
                                                   u16* __restrict__ ctx) {
  // LDS 40960 B: Ks[2] 2x8192B | VT[2] 2x8192B | Ps 4 waves x 2048B
  // Qs (32768B, prologue only) unions with Ks+VT region.
  __shared__ __align__(16) char smem[40960];
  u16* const Qs  = (u16*)smem;
  u16* const Ks  = (u16*)smem;               // + buf*4096 elements
  u16* const VTb = (u16*)(smem + 16384);     // + buf*4096 elements
  const int tid = threadIdx.x;
  const int lane = tid & 63;
  const int w = tid >> 6;
  const int l15 = lane & 15, lhi = lane >> 4;
  u16* const PsW = (u16*)(smem + 32768) + w * 1024;  // [32 q][32 key], e^=(row&6)<<2 swz
  const int qt = blockIdx.x;
  const int bh = blockIdx.y;
  const int b = bh >> 4, h = bh & 15, g = h >> 2;
  const size_t qbase  = ((size_t)(b * 2048 + qt * 128)) * 2048 + h * 128;
  const size_t kbase  = (size_t)b * 1048576 + g * 128;            // k elements
  const size_t vtbase = (size_t)(b * 4 + g) * 262144;             // vt elements

  // ---- prologue: stage Q (swizzled), read qf ----
#pragma unroll
  for (int j = 0; j < 8; ++j) {
    const int c = j * 256 + tid;
    const int row = c >> 4;
    const int dim0 = ((c & 15) ^ (row & 7)) << 3;
    GL2LDS16(q + qbase + (size_t)row * 2048 + dim0, Qs + (size_t)c * 8);
  }
  __syncthreads();
  bf16x8 qf[2][4];
#pragma unroll
  for (int qs = 0; qs < 2; ++qs) {
    const int qrow = w * 32 + qs * 16 + l15;
#pragma unroll
    for (int dk = 0; dk < 4; ++dk) {
      const int el = qrow * 128 + ((dk * 32 + lhi * 8) ^ ((qrow & 7) << 3));
      qf[qs][dk] = *(const bf16x8*)(Qs + el);
    }
  }
  __syncthreads();   // qf reads drained before Ks[0]/VT[0] overwrite

  // staging: K [32 keys][128 dims] row&7 swizzle; V^T [128 dims][32 keys] row&6 swizzle
  auto stageK = [&](int buf, int kt0) {
    u16* Kb = Ks + buf * 4096;
#pragma unroll
    for (int j = 0; j < 2; ++j) {
      const int c = j * 256 + tid;
      const int key = c >> 4;
      const int dim0 = ((c & 15) ^ (key & 7)) << 3;
      GL2LDS16(kbf + kbase + (size_t)(kt0 + key) * 512 + dim0, Kb + (size_t)c * 8);
    }
  };
  auto stageV = [&](int buf, int kt0) {
    u16* Vb = VTb + buf * 4096;
#pragma unroll
    for (int j = 0; j < 2; ++j) {
      const int c = j * 256 + tid;
      const int d = c >> 2;                                  // 0..127
      const int e0 = (((c & 3) << 3) ^ ((d & 6) << 2));      // pre-swizzled source col
      GL2LDS16(vt + vtbase + (size_t)d * 2048 + kt0 + e0, Vb + (size_t)c * 8);
    }
  };

  // ---- stage tile 0 ----
  stageK(0, 0);
  stageV(0, 0);
  __syncthreads();

  f32x4 cacc[8][2] = {};          // O^T: dim = nd*16+lhi*4+r, q = qs*16+l15
  float mrow[2], lrow[2];
#pragma unroll
  for (int qs = 0; qs < 2; ++qs) { mrow[qs] = -3.0e38f; lrow[qs] = 0.f; }

  int cur = 0;
  for (int kt0 = 0; kt0 < 2048; kt0 += 32) {
    const int nxt = cur ^ 1;
    const bool pref = (kt0 + 32) < 2048;
    if (pref) { stageK(nxt, kt0 + 32); stageV(nxt, kt0 + 32); }   // issue-early

    // QK^T swapped: st[ni][qs] = S^T[key = ni*16+lhi*4+r][q = qs*16+l15]
    const u16* Kb = Ks + cur * 4096;
    f32x4 st[2][2] = {};
#pragma unroll
    for (int dk = 0; dk < 4; ++dk) {
      bf16x8 kf[2];
#pragma unroll
      for (int ni = 0; ni < 2; ++ni) {
        const int key = ni * 16 + l15;
        const int el = key * 128 + ((dk * 32 + lhi * 8) ^ ((key & 7) << 3));
        kf[ni] = *(const bf16x8*)(Kb + el);
      }
      __builtin_amdgcn_s_setprio(1);
#pragma unroll
      for (int ni = 0; ni < 2; ++ni)
#pragma unroll
        for (int qs = 0; qs < 2; ++qs)
          st[ni][qs] = __builtin_amdgcn_mfma_f32_16x16x32_bf16(kf[ni], qf[qs][dk], st[ni][qs], 0, 0, 0);
      __builtin_amdgcn_s_setprio(0);
    }

    // online softmax per q-column (scores already in exp2 domain)
#pragma unroll
    for (int qs = 0; qs < 2; ++qs) {
      float pm = -3.0e38f;
#pragma unroll
      for (int ni = 0; ni < 2; ++ni)
#pragma unroll
        for (int r = 0; r < 4; ++r) pm = fmaxf(pm, st[ni][qs][r]);
      pm = fmaxf(pm, __shfl_xor(pm, 16));
      pm = fmaxf(pm, __shfl_xor(pm, 32));
      if (!__all(pm <= mrow[qs] + 8.0f)) {       // defer-max (T13)
        const float mnew = fmaxf(mrow[qs], pm);
        const float f = exp2f(mrow[qs] - mnew);
        mrow[qs] = mnew;
        lrow[qs] *= f;
#pragma unroll
        for (int nd = 0; nd < 8; ++nd) cacc[nd][qs] *= f;
      }
      float ps = 0.f;
      const int row = qs * 16 + l15;
      const int rsw = (row & 6) << 2;
#pragma unroll
      for (int ni = 0; ni < 2; ++ni) {
        const float a0 = exp2f(st[ni][qs][0] - mrow[qs]);
        const float a1 = exp2f(st[ni][qs][1] - mrow[qs]);
        const float a2 = exp2f(st[ni][qs][2] - mrow[qs]);
        const float a3 = exp2f(st[ni][qs][3] - mrow[qs]);
        ps += (a0 + a1) + (a2 + a3);
        uint2 val; val.x = pkbf(a0, a1); val.y = pkbf(a2, a3);
        *(uint2*)(PsW + row * 32 + ((ni * 16 + lhi * 4) ^ rsw)) = val;
      }
      ps += __shfl_xor(ps, 16);
      ps += __shfl_xor(ps, 32);
      lrow[qs] += ps;
    }

    // PV: O^T[dim][q] += V^T * P (single K=32 chunk)
    const u16* Vb = VTb + cur * 4096;
    bf16x8 pf[2];
#pragma unroll
    for (int qs = 0; qs < 2; ++qs) {
      const int row = qs * 16 + l15;
      pf[qs] = *(const bf16x8*)(PsW + row * 32 + ((lhi * 8) ^ ((row & 6) << 2)));
    }
    __builtin_amdgcn_s_setprio(1);
#pragma unroll
    for (int nd = 0; nd < 8; ++nd) {
      const int rowv = nd * 16 + l15;
      const bf16x8 vf = *(const bf16x8*)(Vb + rowv * 32 + ((lhi * 8) ^ ((rowv & 6) << 2)));
#pragma unroll
      for (int qs = 0; qs < 2; ++qs)
        cacc[nd][qs] = __builtin_amdgcn_mfma_f32_16x16x32_bf16(vf, pf[qs], cacc[nd][qs], 0, 0, 0);
    }
    __builtin_amdgcn_s_setprio(0);

    __syncthreads();   // drains gl2lds for nxt + protects buffers
    cur = nxt;
  }

  // epilogue: O^T -> ctx, normalize by row sum
  const int qrow_base = b * 2048 + qt * 128 + w * 32;
#pragma unroll
  for (int qs = 0; qs < 2; ++qs) {
    const float inv = 1.0f / lrow[qs];
    const int row = qrow_base + qs * 16 + l15;
    u16* orow = ctx + (size_t)row * 2048 + h * 128 + lhi * 4;
#pragma unroll
    for (int nd = 0; nd < 8; ++nd) {
      uint2 val;
      val.x = pkbf(cacc[nd][qs][0] * inv, cacc[nd][qs][1] * inv);
      val.y = pkbf(cacc[nd][qs][2] * inv, cacc[nd][qs][3] * inv);
      *(uint2*)(orow + nd * 16) = val;
    }
  }
}

extern "C" void kernel_launch(void* const* d_in, const int* in_sizes, int n_in,
                              void* d_out, int out_size, void* d_ws, size_t ws_size,
                              hipStream_t stream) {
  const float* x_q    = (const float*)d_in[0];
  const float* k_ctx  = (const float*)d_in[1];
  const float* v_ctx  = (const float*)d_in[2];
  const float* w_q    = (const float*)d_in[3];
  const float* w_out  = (const float*)d_in[4];
  const float* norm_w = (const float*)d_in[5];
  float* out = (float*)d_out;

  char* ws = (char*)d_ws;
  u16* wq_bf = (u16*)(ws);
  u16* wo_bf = (u16*)(ws + 8388608);
  u16* k_bf  = (u16*)(ws + 16777216);
  u16* v_t   = (u16*)(ws + 20971520);   // (B,G,128,Tk) bf16, 4 MB
  u16* xn    = (u16*)(ws + 25165824);
  u16* qb    = (u16*)(ws + 41943040);
  u16* ctxb  = xn;  // xn dead after q-proj

  const float kscale = 0.08838834764831845f * 1.4426950408889634f; // 1/sqrt(128)*log2(e)

  cvt3_kernel<<<2048, 256, 0, stream>>>(w_q, w_out, k_ctx, wq_bf, wo_bf, k_bf);
  vtrans_kernel<<<dim3(32, 8, 2), 256, 0, stream>>>(v_ctx, v_t);
  rmsnorm_kernel<<<4096, 256, 0, stream>>>(x_q, norm_w, xn);
  gemm_bt<u16><<<dim3(16, 32), 256, 0, stream>>>(xn, wq_bf, qb, 4096, 2048, 2048, kscale);
  attn_kernel<<<dim3(16, 32), 256, 0, stream>>>(qb, k_bf, v_t, ctxb);
  gemm_bt<float><<<dim3(16, 32), 256, 0, stream>>>(ctxb, wo_bf, out, 4096, 2048, 2048, 1.0f);
}